// Round 7
// baseline (1459.054 us; speedup 1.0000x reference)
//
#include <hip/hip_runtime.h>

// Problem constants (fixed by the reference)
#define M_ROWS 8
#define K_DIM  8192
#define N_DIM  28672

#define BLOCK  512                // 8 waves
#define NPB    8                  // n-rows per block: one per wave
#define KC     2048               // K elements per LDS x-chunk
#define NC     (K_DIM / KC)       // 4 chunks
#define STEPS  (KC / 256)         // 8 k-steps per chunk (256 k per step)

typedef __attribute__((ext_vector_type(4))) int   i32x4;
typedef __attribute__((ext_vector_type(4))) float f32x4;

__global__ __launch_bounds__(BLOCK, 4) void w8a16_gemv_kernel(
    const float* __restrict__ x,      // [M,K] f32 (fp16 values upcast by harness)
    const int*   __restrict__ qw,     // [N,K] int32 (sign-extended int8)
    const float* __restrict__ scales, // [N]   f32
    const float* __restrict__ bias,   // [N]   f32
    float*       __restrict__ out)    // [M,N] f32
{
    // x chunk in LDS: vmem (vmcnt) queue stays exclusively q; x rides lgkm.
    // 64 KiB -> 2 blocks/CU (16 waves/CU). grid=3584 = 14/CU = 7 clean rounds.
    __shared__ float xs[M_ROWS][KC];

    const int tid  = threadIdx.x;
    const int wave = tid >> 6;
    const int lane = tid & 63;
    const int n    = blockIdx.x * NPB + wave;   // one output row per wave
    const int kl   = lane << 2;                 // 4 consecutive k per lane

    const int* qrow = qw + (size_t)n * K_DIM;

    float acc[M_ROWS];
#pragma unroll
    for (int m = 0; m < M_ROWS; ++m) acc[m] = 0.0f;

    for (int c = 0; c < NC; ++c) {
        const int kc = c * KC;

        __syncthreads();   // previous chunk's readers done before overwrite
        // Stage x[0:8, kc:kc+KC] -> LDS. 4096 dwordx4 slots, 512 threads, 8 each.
        // Each wave's 64 slots are consecutive within one row -> linear LDS dest.
#pragma unroll
        for (int i = 0; i < (M_ROWS * KC / 4) / BLOCK; ++i) {
            const int slot = i * BLOCK + tid;     // 0..4095
            const int m    = slot >> 9;           // 512 slots per row
            const int c4   = slot & 511;
            const float* g = &x[(size_t)m * K_DIM + kc + (c4 << 2)];
            __builtin_amdgcn_global_load_lds(
                (const __attribute__((address_space(1))) void*)g,
                (__attribute__((address_space(3))) void*)&xs[m][c4 << 2],
                16, 0, 0);
        }
        __syncthreads();   // stage complete (vmcnt drain covered by other block)

        // Whole chunk fully unrolled: 8 q-loads issue up front (8 KB/wave in
        // flight), vmcnt drains only at the chunk boundary.
#pragma unroll
        for (int s = 0; s < STEPS; ++s) {
            const int kk = s * 256 + kl;

            const i32x4 q4 = __builtin_nontemporal_load(
                reinterpret_cast<const i32x4*>(qrow + kc + kk));

            const float qf0 = (float)q4.x;
            const float qf1 = (float)q4.y;
            const float qf2 = (float)q4.z;
            const float qf3 = (float)q4.w;

#pragma unroll
            for (int m = 0; m < M_ROWS; ++m) {
                const f32x4 xm = *reinterpret_cast<const f32x4*>(&xs[m][kk]);
                acc[m] += xm.x * qf0 + xm.y * qf1 + xm.z * qf2 + xm.w * qf3;
            }
        }
    }

    // Cross-lane reduction (64 lanes) for each of the 8 accumulators.
#pragma unroll
    for (int m = 0; m < M_ROWS; ++m) {
        float v = acc[m];
#pragma unroll
        for (int off = 32; off > 0; off >>= 1)
            v += __shfl_xor(v, off, 64);
        acc[m] = v;
    }

    if (lane == 0) {
        const float s = scales[n];
        const float b = bias[n];
#pragma unroll
        for (int m = 0; m < M_ROWS; ++m)
            out[(size_t)m * N_DIM + n] = s * acc[m] + b;
    }
}

extern "C" void kernel_launch(void* const* d_in, const int* in_sizes, int n_in,
                              void* d_out, int out_size, void* d_ws, size_t ws_size,
                              hipStream_t stream) {
    const float* x      = (const float*)d_in[0];
    const int*   qw     = (const int*)d_in[1];
    const float* scales = (const float*)d_in[2];
    const float* bias   = (const float*)d_in[3];
    float*       out    = (float*)d_out;

    dim3 grid(N_DIM / NPB);   // 3584 blocks = 14 per CU = 7 rounds of 2 resident
    dim3 block(BLOCK);
    w8a16_gemv_kernel<<<grid, block, 0, stream>>>(x, qw, scales, bias, out);
}

// Round 8
// 152.892 us; speedup vs baseline: 9.5430x; 9.5430x over previous
//
#include <hip/hip_runtime.h>

// Problem constants (fixed by the reference)
#define M_ROWS 8
#define K_DIM  8192
#define N_DIM  28672

#define BLOCK   512                       // 8 waves
#define NWAVES  8
#define NPB     112                       // rows per block -> grid = 256 (1/CU)
#define NPW     2                         // rows per wave per sweep
#define SWEEPS  (NPB / (NWAVES * NPW))    // 7
#define KSTEPS  (K_DIM / 256)             // 32 (256 k per wave-step)

typedef __attribute__((ext_vector_type(4))) int      i32x4;
typedef __attribute__((ext_vector_type(4))) float    f32x4;
typedef __attribute__((ext_vector_type(4))) _Float16 f16x4;

__global__ __launch_bounds__(BLOCK, 2) void w8a16_gemv_kernel(
    const float* __restrict__ x,      // [M,K] f32 (values are exact fp16)
    const int*   __restrict__ qw,     // [N,K] int32 (sign-extended int8)
    const float* __restrict__ scales, // [N]   f32
    const float* __restrict__ bias,   // [N]   f32
    float*       __restrict__ out)    // [M,N] f32
{
    // Whole activation matrix lives in LDS for the block's lifetime (fp16 is
    // bit-exact here: harness upcast fp16->f32, we downcast back). 128 KiB ->
    // 1 block/CU; q-stream can never evict it (unlike L1/L2).
    __shared__ _Float16 xs[M_ROWS][K_DIM];

    const int tid  = threadIdx.x;
    const int wave = tid >> 6;
    const int lane = tid & 63;
    const int kl   = lane << 2;           // 4 consecutive k per lane

    // ---- one-time stage: x (256 KB, f32) -> xs (128 KB, fp16) ----
    // vec4 index v = i*512+tid is fully coalesced; waves never straddle rows.
#pragma unroll 4
    for (int i = 0; i < (M_ROWS * K_DIM / 4) / BLOCK; ++i) {   // 32 iters
        const int v = i * BLOCK + tid;                          // f32x4 index
        const f32x4 xv = *reinterpret_cast<const f32x4*>(x + (size_t)v * 4);
        const int e = v * 4;
        const int m = e >> 13;            // e / 8192
        const int c = e & (K_DIM - 1);    // e % 8192
        f16x4 h;
        h.x = (_Float16)xv.x; h.y = (_Float16)xv.y;
        h.z = (_Float16)xv.z; h.w = (_Float16)xv.w;
        *reinterpret_cast<f16x4*>(&xs[m][c]) = h;               // 8 B store
    }
    __syncthreads();   // the ONLY barrier in the kernel

    const int nblock = blockIdx.x * NPB;

    for (int s = 0; s < SWEEPS; ++s) {
        const int n0 = nblock + s * (NWAVES * NPW) + wave * NPW;
        const int* qr0 = qw + (size_t)n0 * K_DIM;
        const int* qr1 = qw + (size_t)(n0 + 1) * K_DIM;

        float acc[NPW][M_ROWS];
#pragma unroll
        for (int j = 0; j < NPW; ++j)
#pragma unroll
            for (int m = 0; m < M_ROWS; ++m) acc[j][m] = 0.0f;

        // Barrier-free K-stream: q is the only vmem traffic; unroll-4 keeps
        // ~8 KB/wave in flight continuously (no drains until sweep end).
#pragma unroll 4
        for (int ks = 0; ks < KSTEPS; ++ks) {
            const int kk = ks * 256 + kl;

            const i32x4 qa = __builtin_nontemporal_load(
                reinterpret_cast<const i32x4*>(qr0 + kk));
            const i32x4 qb = __builtin_nontemporal_load(
                reinterpret_cast<const i32x4*>(qr1 + kk));

            const float qa0 = (float)qa.x, qa1 = (float)qa.y,
                        qa2 = (float)qa.z, qa3 = (float)qa.w;
            const float qb0 = (float)qb.x, qb1 = (float)qb.y,
                        qb2 = (float)qb.z, qb3 = (float)qb.w;

#pragma unroll
            for (int m = 0; m < M_ROWS; ++m) {
                const f16x4 xm = *reinterpret_cast<const f16x4*>(&xs[m][kk]);
                acc[0][m] += (float)xm.x * qa0 + (float)xm.y * qa1
                           + (float)xm.z * qa2 + (float)xm.w * qa3;
                acc[1][m] += (float)xm.x * qb0 + (float)xm.y * qb1
                           + (float)xm.z * qb2 + (float)xm.w * qb3;
            }
        }

        // Cross-lane reduction + store for this sweep's 2 rows.
#pragma unroll
        for (int j = 0; j < NPW; ++j)
#pragma unroll
            for (int m = 0; m < M_ROWS; ++m) {
                float v = acc[j][m];
#pragma unroll
                for (int off = 32; off > 0; off >>= 1)
                    v += __shfl_xor(v, off, 64);
                acc[j][m] = v;
            }

        if (lane == 0) {
#pragma unroll
            for (int j = 0; j < NPW; ++j) {
                const int n = n0 + j;
                const float sc = scales[n];
                const float b  = bias[n];
#pragma unroll
                for (int m = 0; m < M_ROWS; ++m)
                    out[(size_t)m * N_DIM + n] = sc * acc[j][m] + b;
            }
        }
    }
}

extern "C" void kernel_launch(void* const* d_in, const int* in_sizes, int n_in,
                              void* d_out, int out_size, void* d_ws, size_t ws_size,
                              hipStream_t stream) {
    const float* x      = (const float*)d_in[0];
    const int*   qw     = (const int*)d_in[1];
    const float* scales = (const float*)d_in[2];
    const float* bias   = (const float*)d_in[3];
    float*       out    = (float*)d_out;

    dim3 grid(N_DIM / NPB);   // 256 blocks = 1 per CU, perfectly balanced
    dim3 block(BLOCK);
    w8a16_gemv_kernel<<<grid, block, 0, stream>>>(x, qw, scales, bias, out);
}